// Round 8
// baseline (208.142 us; speedup 1.0000x reference)
//
#include <hip/hip_runtime.h>
#include <hip/hip_fp16.h>
#include <math.h>
#include <stdint.h>

#define N_NODES 50000
#define N_EDGES 800000
#define IN_DIM 128
#define H1DIM 64                 // HEADS*HID
#define HEADS 8
#define HID 8
#define OUT_DIM 64
#define NEG_SLOPE 0.2f

#define NB ((N_NODES + 255) / 256)               // 196 buckets (dst>>8)
#define CAP 5120                                 // per-bucket ebuf capacity (mean 4081, +16 sigma)
#define RC2 4                     // score iterations per lane (8 slots -> deg(+self) <= 32)

#define LIN1_WAVES (N_NODES / 16)                // 3125 waves, 16 nodes each (MFMA tile)
#define LIN1_BLOCKS ((LIN1_WAVES + 3) / 4)       // 782

#define EPT 8                                    // edges per thread (scatter)
#define HB ((N_EDGES + 256*EPT - 1) / (256*EPT)) // 391 scatter blocks

typedef _Float16 half8 __attribute__((ext_vector_type(8)));
typedef float f32x4 __attribute__((ext_vector_type(4)));

__device__ __forceinline__ float lrelu(float v) { return v >= 0.f ? v : NEG_SLOPE * v; }

// unpack 8 fp16 (raw uint4) and FMA into a[8]
__device__ __forceinline__ void fma8raw(uint4 u, float alpha, float* a) {
    float2 f0 = __half22float2(*(const __half2*)&u.x);
    float2 f1 = __half22float2(*(const __half2*)&u.y);
    float2 f2 = __half22float2(*(const __half2*)&u.z);
    float2 f3 = __half22float2(*(const __half2*)&u.w);
    a[0] += f0.x * alpha; a[1] += f0.y * alpha;
    a[2] += f1.x * alpha; a[3] += f1.y * alpha;
    a[4] += f2.x * alpha; a[5] += f2.y * alpha;
    a[6] += f3.x * alpha; a[7] += f3.y * alpha;
}

__device__ __forceinline__ void fma8h(const __half* __restrict__ base, float alpha, float* a) {
    fma8raw(*reinterpret_cast<const uint4*>(base), alpha, a);
}

// ---------------- prep: W1 -> fragment-ordered hi/lo global blobs + zero cursors ----
// fragset f = ks*4+ct: B operand for K-step ks, col-tile ct. Lane l, elem j:
// k = ks*32+(l>>4)*8+j, c = ct*16+(l&15). idx = f*512 + l*8 + j.

__global__ __launch_bounds__(256) void prep_kernel(
    const float* __restrict__ W1,
    __half* __restrict__ w1fH, __half* __restrict__ w1fL,
    int* __restrict__ cursor)
{
    int b = blockIdx.x;
    if (b < 32) {                         // W1: 8192 elems
        int idx = b * 256 + threadIdx.x;
        int f = idx >> 9, rr = idx & 511;
        int l = rr >> 3, j = rr & 7;
        int ks = f >> 2, ct = f & 3;
        int k = ks * 32 + ((l >> 4) << 3) + j;
        int c = (ct << 4) + (l & 15);
        float w = W1[k * 64 + c];
        __half hi = __float2half(w);
        w1fH[idx] = hi;
        w1fL[idx] = __float2half(w - __half2float(hi));
    } else {
        for (int k = threadIdx.x; k < 16 * NB; k += 256) cursor[k] = 0;
    }
}

// ---------------- fused: edge scatter into fixed-cap buckets (blocks [0,HB)) +
//                  lin1 via split-fp16 MFMA (rest) ----------------

__global__ __launch_bounds__(256) void cl1_kernel(
    const int* __restrict__ ei, int* __restrict__ cursor, int* __restrict__ ebuf,
    const float* __restrict__ x,
    const __half* __restrict__ w1fH, const __half* __restrict__ w1fL,
    const float* __restrict__ a_src, const float* __restrict__ a_dst,
    __half* __restrict__ h1, float* __restrict__ ssrc, float* __restrict__ sdst)
{
    __shared__ int hist[NB];
    __shared__ int res[NB];
    if (blockIdx.x < HB) {
        for (int k = threadIdx.x; k < NB; k += 256) hist[k] = 0;
        __syncthreads();
        int base = blockIdx.x * (256 * EPT) + threadIdx.x;
        int ss[EPT], ds[EPT];
        #pragma unroll
        for (int j = 0; j < EPT; ++j) {
            int e = base + j * 256;
            ds[j] = -1;
            if (e < N_EDGES) {
                ss[j] = ei[e];
                ds[j] = ei[N_EDGES + e];
                atomicAdd(&hist[ds[j] >> 8], 1);
            }
        }
        __syncthreads();
        if (threadIdx.x < NB) {
            int h = hist[threadIdx.x];
            res[threadIdx.x] = h ? atomicAdd(&cursor[threadIdx.x * 16], h) : 0;
            hist[threadIdx.x] = 0;
        }
        __syncthreads();
        #pragma unroll
        for (int j = 0; j < EPT; ++j) {
            if (ds[j] >= 0) {
                int b = ds[j] >> 8;
                int r = atomicAdd(&hist[b], 1);
                int idx = res[b] + r;
                if (idx < CAP) ebuf[b * CAP + idx] = ss[j] | ((ds[j] & 255) << 16);
            }
        }
        return;
    }

    int wid = threadIdx.x >> 6, t = threadIdx.x & 63;
    int g = (blockIdx.x - HB) * 4 + wid;
    if (g >= LIN1_WAVES) return;
    int n0 = g * 16;
    int row = t & 15, kq = t >> 4;

    f32x4 acc[4] = {};
    const float* xp = x + (size_t)(n0 + row) * IN_DIM + kq * 8;
    #pragma unroll
    for (int ks = 0; ks < 4; ++ks) {
        float4 u0 = *reinterpret_cast<const float4*>(xp + ks * 32);
        float4 u1 = *reinterpret_cast<const float4*>(xp + ks * 32 + 4);
        float xv[8] = {u0.x, u0.y, u0.z, u0.w, u1.x, u1.y, u1.z, u1.w};
        half8 ah, al;
        #pragma unroll
        for (int j = 0; j < 8; ++j) {
            _Float16 h = (_Float16)xv[j];
            ah[j] = h;
            al[j] = (_Float16)(xv[j] - (float)h);
        }
        #pragma unroll
        for (int ct = 0; ct < 4; ++ct) {
            int f = ks * 4 + ct;
            half8 bh = *reinterpret_cast<const half8*>(w1fH + f * 512 + t * 8);
            half8 bl = *reinterpret_cast<const half8*>(w1fL + f * 512 + t * 8);
            acc[ct] = __builtin_amdgcn_mfma_f32_16x16x32_f16(ah, bh, acc[ct], 0, 0, 0);
            acc[ct] = __builtin_amdgcn_mfma_f32_16x16x32_f16(al, bh, acc[ct], 0, 0, 0);
            acc[ct] = __builtin_amdgcn_mfma_f32_16x16x32_f16(ah, bl, acc[ct], 0, 0, 0);
        }
    }

    float asv[4], adv[4];
    #pragma unroll
    for (int ct = 0; ct < 4; ++ct) {
        asv[ct] = a_src[ct * 16 + (t & 15)];
        adv[ct] = a_dst[ct * 16 + (t & 15)];
    }
    int rbase = n0 + (t >> 4) * 4;
    #pragma unroll
    for (int r = 0; r < 4; ++r) {
        int n = rbase + r;
        #pragma unroll
        for (int ct = 0; ct < 4; ++ct) {
            float v = acc[ct][r];
            h1[(size_t)n * 64 + ct * 16 + (t & 15)] = __float2half(v);
            float ps = v * asv[ct], pd = v * adv[ct];
            ps += __shfl_xor(ps, 1); ps += __shfl_xor(ps, 2); ps += __shfl_xor(ps, 4);
            pd += __shfl_xor(pd, 1); pd += __shfl_xor(pd, 2); pd += __shfl_xor(pd, 4);
            if ((t & 7) == 0) {
                int hd = ct * 2 + ((t >> 3) & 1);
                ssrc[n * 8 + hd] = ps;
                sdst[n * 8 + hd] = pd;
            }
        }
    }
}

// ---------------- p2: per-bucket CSR build (1 block per bucket, 512 thr) ----
// Pure-edge CSR (self-loops handled analytically in l1x/l2). In-block
// 196-wide scan recomputes ebase. LDS count -> LDS scan -> rowp + scatter.

__global__ __launch_bounds__(512) void p2_kernel(
    const int* __restrict__ cursor, const int* __restrict__ ebuf,
    int* __restrict__ rowp, int* __restrict__ adj)
{
    __shared__ int sb[256];
    __shared__ int cnt[256];
    __shared__ int sh[256];
    __shared__ int cur[256];
    int b = blockIdx.x, t = threadIdx.x;

    if (t < 256) {
        int c = (t < NB) ? cursor[t * 16] : 0;
        sb[t] = c < CAP ? c : CAP;
    }
    __syncthreads();
    #pragma unroll
    for (int o = 1; o < 256; o <<= 1) {
        int add = (t < 256 && t >= o) ? sb[t - o] : 0;
        __syncthreads();
        if (t < 256) sb[t] += add;
        __syncthreads();
    }
    int m = cursor[b * 16]; if (m > CAP) m = CAP;
    int eb0 = sb[b] - m;                  // ebase[b]

    int n0 = b * 256;
    int nn = N_NODES - n0; if (nn > 256) nn = 256;
    if (t < 256) cnt[t] = 0;
    __syncthreads();
    const int* eb = ebuf + b * CAP;
    for (int e = t; e < m; e += 512)
        atomicAdd(&cnt[eb[e] >> 16], 1);
    __syncthreads();
    int myc = (t < 256) ? cnt[t] : 0;
    if (t < 256) sh[t] = myc;
    __syncthreads();
    #pragma unroll
    for (int o = 1; o < 256; o <<= 1) {
        int add = (t < 256 && t >= o) ? sh[t - o] : 0;
        __syncthreads();
        if (t < 256) sh[t] += add;
        __syncthreads();
    }
    if (t < 256) {
        int myoff = eb0 + sh[t] - myc;
        cur[t] = myoff;
        if (t < nn) rowp[n0 + t] = myoff;
        if (b == 0 && t == 0) rowp[N_NODES] = N_EDGES;
    }
    __syncthreads();
    for (int e = t; e < m; e += 512) {
        int v = eb[e];
        int r = atomicAdd(&cur[v >> 16], 1);
        adj[r] = v & 0xFFFF;
    }
}

// ---------------- fused layer-1 node kernel + in-wave lin2 ----------------
// 1 node per wave; slot = t>>3 (8 slots), h = t&7. Virtual self-loop at edge
// position `end` (score cond e<=end; s defaults to n). After aggregation the
// wave holds the full 64-ch ha row replicated (channel c in a[c&7] of lanes
// ==c>>3 mod 8) -> lin2 via 64x {shfl-broadcast x W2 column} per lane, no LDS.

__global__ __launch_bounds__(256) void l1x_kernel(
    const int* __restrict__ row, const int* __restrict__ adj,
    const __half* __restrict__ h1, const float* __restrict__ s1, const float* __restrict__ t1,
    const float* __restrict__ b1, const float* __restrict__ W2,
    const float* __restrict__ as2, const float* __restrict__ ad2,
    __half* __restrict__ h2, float* __restrict__ s2, float* __restrict__ t2)
{
    int wid = threadIdx.x >> 6, t = threadIdx.x & 63;
    int n = blockIdx.x * 4 + wid;
    int beg = row[n], end = row[n + 1];
    int slot = t >> 3, h = t & 7;
    float sd = t1[n * 8 + h];
    const int e0 = beg + slot;

    // gather scores (+virtual self at e==end) + prefetch ALL feature rows
    float p[RC2];
    uint4 raw[RC2];
    float m = -3e38f;
    #pragma unroll
    for (int it = 0; it < RC2; ++it) {
        int e = e0 + it * 8;
        int s = (e < end) ? adj[e] : n;
        float v = (e <= end) ? lrelu(s1[s * 8 + h] + sd) : -3e38f;
        p[it] = v;
        m = fmaxf(m, v);
        raw[it] = *reinterpret_cast<const uint4*>(h1 + (size_t)s * 64 + h * 8);
    }
    for (int e = e0 + RC2 * 8; e <= end; e += 8) {   // improbable tail (deg >= 32)
        int s = (e < end) ? adj[e] : n;
        m = fmaxf(m, lrelu(s1[s * 8 + h] + sd));
    }
    m = fmaxf(m, __shfl_xor(m, 8));
    m = fmaxf(m, __shfl_xor(m, 16));
    m = fmaxf(m, __shfl_xor(m, 32));

    float den = 0.f;
    #pragma unroll
    for (int it = 0; it < RC2; ++it) {
        float pe = __expf(p[it] - m);             // empty slots -> 0
        p[it] = pe;
        den += pe;
    }
    for (int e = e0 + RC2 * 8; e <= end; e += 8) {
        int s = (e < end) ? adj[e] : n;
        den += __expf(lrelu(s1[s * 8 + h] + sd) - m);
    }
    den += __shfl_xor(den, 8);
    den += __shfl_xor(den, 16);
    den += __shfl_xor(den, 32);
    float inv = 1.f / (den + 1e-16f);

    // aggregate: lane accumulates channels h*8..h*8+7
    float a[8] = {0,0,0,0,0,0,0,0};
    #pragma unroll
    for (int it = 0; it < RC2; ++it) fma8raw(raw[it], p[it] * inv, a);
    for (int e = e0 + RC2 * 8; e <= end; e += 8) {
        int s = (e < end) ? adj[e] : n;
        float alpha = __expf(lrelu(s1[s * 8 + h] + sd) - m) * inv;
        fma8h(h1 + (size_t)s * 64 + h * 8, alpha, a);
    }
    #pragma unroll
    for (int j = 0; j < 8; ++j) {
        a[j] += __shfl_xor(a[j], 8);
        a[j] += __shfl_xor(a[j], 16);
        a[j] += __shfl_xor(a[j], 32);
    }

    // bias + ELU (all lanes; a[j] = channel (t&7)*8+j, replicated)
    float ae[8];
    #pragma unroll
    for (int j = 0; j < 8; ++j) {
        float v = a[j] + b1[h * 8 + j];
        ae[j] = v > 0.f ? v : (__expf(v) - 1.f);
    }

    // in-wave lin2: lane t computes out column t; channel k lives in
    // ae[k&7] of lane (k>>3) (uniform shfl -> readlane broadcast)
    float c0 = 0.f;
    #pragma unroll 8
    for (int k = 0; k < 64; ++k) {
        float hk = __shfl(ae[k & 7], k >> 3);
        c0 += hk * W2[k * 64 + t];
    }
    h2[(size_t)n * 64 + t] = __float2half(c0);

    // layer-2 scores (full-wave reduce)
    float rs = c0 * as2[t];
    float rd = c0 * ad2[t];
    #pragma unroll
    for (int mk = 32; mk >= 1; mk >>= 1) {
        rs += __shfl_xor(rs, mk);
        rd += __shfl_xor(rd, mk);
    }
    if (t == 0) { s2[n] = rs; t2[n] = rd; }
}

// ---------------- layer-2 node kernel: 1 node per wave ----------------
// virtual self-loop at e==end, same as l1x.

__global__ __launch_bounds__(256) void l2_kernel(
    const int* __restrict__ row, const int* __restrict__ adj,
    const __half* __restrict__ h2, const float* __restrict__ s2, const float* __restrict__ t2,
    const float* __restrict__ b2, float* __restrict__ out)
{
    int wid = threadIdx.x >> 6, t = threadIdx.x & 63;
    int n = blockIdx.x * 4 + wid;
    int beg = row[n], end = row[n + 1];
    int slot = t >> 3, g = t & 7;
    float sd = t2[n];
    const int e0 = beg + slot;

    float p[RC2];
    uint4 raw[RC2];
    float m = -3e38f;
    #pragma unroll
    for (int it = 0; it < RC2; ++it) {
        int e = e0 + it * 8;
        int s = (e < end) ? adj[e] : n;
        float v = (e <= end) ? lrelu(s2[s] + sd) : -3e38f;
        p[it] = v;
        m = fmaxf(m, v);
        raw[it] = *reinterpret_cast<const uint4*>(h2 + (size_t)s * 64 + g * 8);
    }
    for (int e = e0 + RC2 * 8; e <= end; e += 8) {
        int s = (e < end) ? adj[e] : n;
        m = fmaxf(m, lrelu(s2[s] + sd));
    }
    m = fmaxf(m, __shfl_xor(m, 8));
    m = fmaxf(m, __shfl_xor(m, 16));
    m = fmaxf(m, __shfl_xor(m, 32));

    float den = 0.f;
    #pragma unroll
    for (int it = 0; it < RC2; ++it) {
        float pe = __expf(p[it] - m);
        p[it] = pe;
        den += pe;
    }
    for (int e = e0 + RC2 * 8; e <= end; e += 8) {
        int s = (e < end) ? adj[e] : n;
        den += __expf(lrelu(s2[s] + sd) - m);
    }
    den += __shfl_xor(den, 8);
    den += __shfl_xor(den, 16);
    den += __shfl_xor(den, 32);
    float inv = 1.f / (den + 1e-16f);

    float a[8] = {0,0,0,0,0,0,0,0};
    #pragma unroll
    for (int it = 0; it < RC2; ++it) fma8raw(raw[it], p[it] * inv, a);
    for (int e = e0 + RC2 * 8; e <= end; e += 8) {
        int s = (e < end) ? adj[e] : n;
        float alpha = __expf(lrelu(s2[s] + sd) - m) * inv;
        fma8h(h2 + (size_t)s * 64 + g * 8, alpha, a);
    }
    #pragma unroll
    for (int j = 0; j < 8; ++j) {
        a[j] += __shfl_xor(a[j], 8);
        a[j] += __shfl_xor(a[j], 16);
        a[j] += __shfl_xor(a[j], 32);
    }
    if (slot == 0) {
        float4 o0 = make_float4(a[0] + b2[g * 8 + 0], a[1] + b2[g * 8 + 1],
                                a[2] + b2[g * 8 + 2], a[3] + b2[g * 8 + 3]);
        float4 o1 = make_float4(a[4] + b2[g * 8 + 4], a[5] + b2[g * 8 + 5],
                                a[6] + b2[g * 8 + 6], a[7] + b2[g * 8 + 7]);
        float4* op = (float4*)(out + (size_t)n * 64 + g * 8);
        op[0] = o0; op[1] = o1;
    }
}

extern "C" void kernel_launch(void* const* d_in, const int* in_sizes, int n_in,
                              void* d_out, int out_size, void* d_ws, size_t ws_size,
                              hipStream_t stream)
{
    const float* x   = (const float*)d_in[0];
    const int* ei    = (const int*)d_in[1];
    const float* W1  = (const float*)d_in[2];
    const float* as1 = (const float*)d_in[3];
    const float* ad1 = (const float*)d_in[4];
    const float* b1  = (const float*)d_in[5];
    const float* W2  = (const float*)d_in[6];
    const float* as2 = (const float*)d_in[7];
    const float* ad2 = (const float*)d_in[8];
    const float* b2  = (const float*)d_in[9];
    float* out = (float*)d_out;

    char* wsb = (char*)d_ws;
    __half* h1   = (__half*)wsb;                      // N*64 fp16
    __half* h2   = h1 + (size_t)N_NODES * 64;         // N*64 fp16
    __half* w1fH = h2 + (size_t)N_NODES * 64;         // 8192
    __half* w1fL = w1fH + 8192;                       // 8192
    float*  s1   = (float*)(w1fL + 8192);             // N*8
    float*  t1   = s1 + N_NODES * 8;                  // N*8
    float*  s2   = t1 + N_NODES * 8;                  // N
    float*  t2   = s2 + N_NODES;                      // N
    int*    cursor = (int*)(t2 + N_NODES);            // 16*NB (line-padded)
    int*    rowp   = cursor + 16 * NB;                // N+1
    int*    adj    = rowp + N_NODES + 1;              // N_EDGES
    int*    ebuf   = adj + N_EDGES;                   // NB*CAP

    prep_kernel<<<33, 256, 0, stream>>>(W1, w1fH, w1fL, cursor);

    cl1_kernel<<<HB + LIN1_BLOCKS, 256, 0, stream>>>(ei, cursor, ebuf, x, w1fH, w1fL,
                                                     as1, ad1, h1, s1, t1);

    p2_kernel<<<NB, 512, 0, stream>>>(cursor, ebuf, rowp, adj);

    l1x_kernel<<<N_NODES / 4, 256, 0, stream>>>(rowp, adj, h1, s1, t1, b1,
                                                W2, as2, ad2, h2, s2, t2);

    l2_kernel<<<N_NODES / 4, 256, 0, stream>>>(rowp, adj, h2, s2, t2, b2, out);
}

// Round 10
// 186.508 us; speedup vs baseline: 1.1160x; 1.1160x over previous
//
#include <hip/hip_runtime.h>
#include <hip/hip_fp16.h>
#include <math.h>
#include <stdint.h>

#define N_NODES 50000
#define N_EDGES 800000
#define ET (N_EDGES + N_NODES)   // edges + self loops
#define IN_DIM 128
#define H1DIM 64                 // HEADS*HID
#define HEADS 8
#define HID 8
#define OUT_DIM 64
#define NEG_SLOPE 0.2f

#define NB ((N_NODES + 255) / 256)               // 196 buckets (dst>>8)
#define CAP 5120                                 // per-bucket ebuf capacity (mean 4081, +16 sigma)
#define RC2 4                     // score iterations per lane (8 slots -> deg <= 32)

#define LIN1_WAVES (N_NODES / 16)                // 3125 waves, 16 nodes each (MFMA tile)
#define LIN1_BLOCKS ((LIN1_WAVES + 3) / 4)       // 782

#define EPT 8                                    // edges per thread (scatter)
#define HB ((N_EDGES + 256*EPT - 1) / (256*EPT)) // 391 scatter blocks

typedef _Float16 half8 __attribute__((ext_vector_type(8)));
typedef float f32x4 __attribute__((ext_vector_type(4)));

__device__ __forceinline__ float lrelu(float v) { return v >= 0.f ? v : NEG_SLOPE * v; }

// unpack 8 fp16 (raw uint4) and FMA into a[8]
__device__ __forceinline__ void fma8raw(uint4 u, float alpha, float* a) {
    float2 f0 = __half22float2(*(const __half2*)&u.x);
    float2 f1 = __half22float2(*(const __half2*)&u.y);
    float2 f2 = __half22float2(*(const __half2*)&u.z);
    float2 f3 = __half22float2(*(const __half2*)&u.w);
    a[0] += f0.x * alpha; a[1] += f0.y * alpha;
    a[2] += f1.x * alpha; a[3] += f1.y * alpha;
    a[4] += f2.x * alpha; a[5] += f2.y * alpha;
    a[6] += f3.x * alpha; a[7] += f3.y * alpha;
}

__device__ __forceinline__ void fma8h(const __half* __restrict__ base, float alpha, float* a) {
    fma8raw(*reinterpret_cast<const uint4*>(base), alpha, a);
}

// ---------------- prep: W1/W2 -> fragment-ordered hi/lo global blobs + zero cursors ----
// fragset f = ks*4+ct: B operand for K-step ks, col-tile ct. Lane l, elem j:
// k = ks*32+(l>>4)*8+j, c = ct*16+(l&15). idx = f*512 + l*8 + j.

__global__ __launch_bounds__(256) void prep_kernel(
    const float* __restrict__ W1, const float* __restrict__ W2,
    __half* __restrict__ w1fH, __half* __restrict__ w1fL,
    __half* __restrict__ w2fH, __half* __restrict__ w2fL,
    int* __restrict__ cursor)
{
    int b = blockIdx.x;
    if (b < 32) {                         // W1: 8192 elems
        int idx = b * 256 + threadIdx.x;
        int f = idx >> 9, rr = idx & 511;
        int l = rr >> 3, j = rr & 7;
        int ks = f >> 2, ct = f & 3;
        int k = ks * 32 + ((l >> 4) << 3) + j;
        int c = (ct << 4) + (l & 15);
        float w = W1[k * 64 + c];
        __half hi = __float2half(w);
        w1fH[idx] = hi;
        w1fL[idx] = __float2half(w - __half2float(hi));
    } else if (b < 48) {                  // W2: 4096 elems
        int idx = (b - 32) * 256 + threadIdx.x;
        int f = idx >> 9, rr = idx & 511;
        int l = rr >> 3, j = rr & 7;
        int ks = f >> 2, ct = f & 3;
        int k = ks * 32 + ((l >> 4) << 3) + j;
        int c = (ct << 4) + (l & 15);
        float w = W2[k * 64 + c];
        __half hi = __float2half(w);
        w2fH[idx] = hi;
        w2fL[idx] = __float2half(w - __half2float(hi));
    } else {
        for (int k = threadIdx.x; k < 16 * NB; k += 256) cursor[k] = 0;
    }
}

// ---------------- fused: edge scatter into fixed-cap buckets (blocks [0,HB)) +
//                  lin1 via split-fp16 MFMA (rest) ----------------

__global__ __launch_bounds__(256) void cl1_kernel(
    const int* __restrict__ ei, int* __restrict__ cursor, int* __restrict__ ebuf,
    const float* __restrict__ x,
    const __half* __restrict__ w1fH, const __half* __restrict__ w1fL,
    const float* __restrict__ a_src, const float* __restrict__ a_dst,
    __half* __restrict__ h1, float* __restrict__ ssrc, float* __restrict__ sdst)
{
    __shared__ int hist[NB];
    __shared__ int res[NB];
    if (blockIdx.x < HB) {
        for (int k = threadIdx.x; k < NB; k += 256) hist[k] = 0;
        __syncthreads();
        int base = blockIdx.x * (256 * EPT) + threadIdx.x;
        int ss[EPT], ds[EPT];
        #pragma unroll
        for (int j = 0; j < EPT; ++j) {
            int e = base + j * 256;
            ds[j] = -1;
            if (e < N_EDGES) {
                ss[j] = ei[e];
                ds[j] = ei[N_EDGES + e];
                atomicAdd(&hist[ds[j] >> 8], 1);
            }
        }
        __syncthreads();
        if (threadIdx.x < NB) {
            int h = hist[threadIdx.x];
            res[threadIdx.x] = h ? atomicAdd(&cursor[threadIdx.x * 16], h) : 0;
            hist[threadIdx.x] = 0;
        }
        __syncthreads();
        #pragma unroll
        for (int j = 0; j < EPT; ++j) {
            if (ds[j] >= 0) {
                int b = ds[j] >> 8;
                int r = atomicAdd(&hist[b], 1);
                int idx = res[b] + r;
                if (idx < CAP) ebuf[b * CAP + idx] = ss[j] | ((ds[j] & 255) << 16);
            }
        }
        return;
    }

    int wid = threadIdx.x >> 6, t = threadIdx.x & 63;
    int g = (blockIdx.x - HB) * 4 + wid;
    if (g >= LIN1_WAVES) return;
    int n0 = g * 16;
    int row = t & 15, kq = t >> 4;

    f32x4 acc[4] = {};
    const float* xp = x + (size_t)(n0 + row) * IN_DIM + kq * 8;
    #pragma unroll
    for (int ks = 0; ks < 4; ++ks) {
        float4 u0 = *reinterpret_cast<const float4*>(xp + ks * 32);
        float4 u1 = *reinterpret_cast<const float4*>(xp + ks * 32 + 4);
        float xv[8] = {u0.x, u0.y, u0.z, u0.w, u1.x, u1.y, u1.z, u1.w};
        half8 ah, al;
        #pragma unroll
        for (int j = 0; j < 8; ++j) {
            _Float16 h = (_Float16)xv[j];
            ah[j] = h;
            al[j] = (_Float16)(xv[j] - (float)h);
        }
        #pragma unroll
        for (int ct = 0; ct < 4; ++ct) {
            int f = ks * 4 + ct;
            half8 bh = *reinterpret_cast<const half8*>(w1fH + f * 512 + t * 8);
            half8 bl = *reinterpret_cast<const half8*>(w1fL + f * 512 + t * 8);
            acc[ct] = __builtin_amdgcn_mfma_f32_16x16x32_f16(ah, bh, acc[ct], 0, 0, 0);
            acc[ct] = __builtin_amdgcn_mfma_f32_16x16x32_f16(al, bh, acc[ct], 0, 0, 0);
            acc[ct] = __builtin_amdgcn_mfma_f32_16x16x32_f16(ah, bl, acc[ct], 0, 0, 0);
        }
    }

    float asv[4], adv[4];
    #pragma unroll
    for (int ct = 0; ct < 4; ++ct) {
        asv[ct] = a_src[ct * 16 + (t & 15)];
        adv[ct] = a_dst[ct * 16 + (t & 15)];
    }
    int rbase = n0 + (t >> 4) * 4;
    #pragma unroll
    for (int r = 0; r < 4; ++r) {
        int n = rbase + r;
        #pragma unroll
        for (int ct = 0; ct < 4; ++ct) {
            float v = acc[ct][r];
            h1[(size_t)n * 64 + ct * 16 + (t & 15)] = __float2half(v);
            float ps = v * asv[ct], pd = v * adv[ct];
            ps += __shfl_xor(ps, 1); ps += __shfl_xor(ps, 2); ps += __shfl_xor(ps, 4);
            pd += __shfl_xor(pd, 1); pd += __shfl_xor(pd, 2); pd += __shfl_xor(pd, 4);
            if ((t & 7) == 0) {
                int hd = ct * 2 + ((t >> 3) & 1);
                ssrc[n * 8 + hd] = ps;
                sdst[n * 8 + hd] = pd;
            }
        }
    }
}

// ---------------- p2: per-bucket CSR build (1 block per bucket, 512 thr) ----
// in-block 196-wide scan recomputes ebase. LDS count -> LDS scan -> rowp +
// LDS-cursor scatter into adj. Self-loop written at each node's last slot
// after the scatter (cnt included +1 for it, so ranks never collide).

__global__ __launch_bounds__(512) void p2_kernel(
    const int* __restrict__ cursor, const int* __restrict__ ebuf,
    int* __restrict__ rowp, int* __restrict__ adj)
{
    __shared__ int sb[256];
    __shared__ int cnt[256];
    __shared__ int sh[256];
    __shared__ int cur[256];
    int b = blockIdx.x, t = threadIdx.x;

    if (t < 256) sb[t] = (t < NB) ? cursor[t * 16] : 0;
    __syncthreads();
    #pragma unroll
    for (int o = 1; o < 256; o <<= 1) {
        int add = (t < 256 && t >= o) ? sb[t - o] : 0;
        __syncthreads();
        if (t < 256) sb[t] += add;
        __syncthreads();
    }
    int m = cursor[b * 16];
    int eb0 = sb[b] - m;                  // ebase[b]

    int n0 = b * 256;
    int nn = N_NODES - n0; if (nn > 256) nn = 256;
    if (t < 256) cnt[t] = (t < nn) ? 1 : 0;   // analytic self-loop
    __syncthreads();
    const int* eb = ebuf + b * CAP;
    for (int e = t; e < m; e += 512)
        atomicAdd(&cnt[eb[e] >> 16], 1);
    __syncthreads();
    int myc = (t < 256) ? cnt[t] : 0;
    if (t < 256) sh[t] = myc;
    __syncthreads();
    #pragma unroll
    for (int o = 1; o < 256; o <<= 1) {
        int add = (t < 256 && t >= o) ? sh[t - o] : 0;
        __syncthreads();
        if (t < 256) sh[t] += add;
        __syncthreads();
    }
    int ab = eb0 + n0;                    // adj base of bucket
    int myoff = 0;
    if (t < 256) {
        myoff = ab + sh[t] - myc;
        cur[t] = myoff;
        if (t < nn) rowp[n0 + t] = myoff;
        if (b == 0 && t == 0) rowp[N_NODES] = ET;
    }
    __syncthreads();
    for (int e = t; e < m; e += 512) {
        int v = eb[e];
        int r = atomicAdd(&cur[v >> 16], 1);
        adj[r] = v & 0xFFFF;
    }
    __syncthreads();
    if (t < nn) adj[myoff + myc - 1] = n0 + t;   // self-loop at last slot
}

// ---------------- layer-1 node kernel: 1 node per wave ----------------

__global__ __launch_bounds__(256) void l1_kernel(
    const int* __restrict__ row, const int* __restrict__ adj,
    const __half* __restrict__ h1, const float* __restrict__ s1, const float* __restrict__ t1,
    const float* __restrict__ b1, __half* __restrict__ ha)
{
    int wid = threadIdx.x >> 6, t = threadIdx.x & 63;
    int n = blockIdx.x * 4 + wid;
    int beg = row[n], end = row[n + 1];
    int slot = t >> 3, h = t & 7;
    float sd = t1[n * 8 + h];
    const int e0 = beg + slot;

    float p[RC2];
    uint4 raw[RC2];
    float m = -3e38f;
    #pragma unroll
    for (int it = 0; it < RC2; ++it) {
        int e = e0 + it * 8;
        bool ok = e < end;
        int s = ok ? adj[e] : n;
        float v = ok ? lrelu(s1[s * 8 + h] + sd) : -3e38f;
        p[it] = v;
        m = fmaxf(m, v);
        raw[it] = *reinterpret_cast<const uint4*>(h1 + (size_t)s * 64 + h * 8);
    }
    for (int e = e0 + RC2 * 8; e < end; e += 8)
        m = fmaxf(m, lrelu(s1[adj[e] * 8 + h] + sd));
    m = fmaxf(m, __shfl_xor(m, 8));
    m = fmaxf(m, __shfl_xor(m, 16));
    m = fmaxf(m, __shfl_xor(m, 32));

    float den = 0.f;
    #pragma unroll
    for (int it = 0; it < RC2; ++it) {
        float pe = __expf(p[it] - m);
        p[it] = pe;
        den += pe;
    }
    for (int e = e0 + RC2 * 8; e < end; e += 8)
        den += __expf(lrelu(s1[adj[e] * 8 + h] + sd) - m);
    den += __shfl_xor(den, 8);
    den += __shfl_xor(den, 16);
    den += __shfl_xor(den, 32);
    float inv = 1.f / (den + 1e-16f);

    float a[8] = {0,0,0,0,0,0,0,0};
    #pragma unroll
    for (int it = 0; it < RC2; ++it) fma8raw(raw[it], p[it] * inv, a);
    for (int e = e0 + RC2 * 8; e < end; e += 8) {
        int s = adj[e];
        float alpha = __expf(lrelu(s1[s * 8 + h] + sd) - m) * inv;
        fma8h(h1 + (size_t)s * 64 + h * 8, alpha, a);
    }
    #pragma unroll
    for (int j = 0; j < 8; ++j) {
        a[j] += __shfl_xor(a[j], 8);
        a[j] += __shfl_xor(a[j], 16);
        a[j] += __shfl_xor(a[j], 32);
    }

    if (slot < 4) {
        int j0 = slot * 2;
        float v0 = a[j0]     + b1[h * 8 + j0];
        float v1 = a[j0 + 1] + b1[h * 8 + j0 + 1];
        v0 = v0 > 0.f ? v0 : (__expf(v0) - 1.f);
        v1 = v1 > 0.f ? v1 : (__expf(v1) - 1.f);
        __half2 hv;
        hv.x = __float2half(v0);
        hv.y = __float2half(v1);
        *reinterpret_cast<__half2*>(ha + (size_t)n * 64 + h * 8 + j0) = hv;
    }
}

// ---------------- lin2 via fp16 MFMA: h2 = ha @ W2, + layer-2 scores ----

__global__ __launch_bounds__(256) void lin2_kernel(
    const __half* __restrict__ ha,
    const __half* __restrict__ w2fH, const __half* __restrict__ w2fL,
    const float* __restrict__ as2, const float* __restrict__ ad2,
    __half* __restrict__ h2, float* __restrict__ s2, float* __restrict__ t2)
{
    int tid = threadIdx.x;
    int wid = tid >> 6, t = tid & 63;
    int g = blockIdx.x * 4 + wid;
    if (g >= LIN1_WAVES) return;
    int n0 = g * 16;
    int row = t & 15, kq = t >> 4;

    f32x4 acc[4] = {};
    const __half* xp = ha + (size_t)(n0 + row) * 64 + kq * 8;
    #pragma unroll
    for (int ks = 0; ks < 2; ++ks) {
        half8 ahv = *reinterpret_cast<const half8*>(xp + ks * 32);
        #pragma unroll
        for (int ct = 0; ct < 4; ++ct) {
            int f = ks * 4 + ct;
            half8 bh = *reinterpret_cast<const half8*>(w2fH + f * 512 + t * 8);
            half8 bl = *reinterpret_cast<const half8*>(w2fL + f * 512 + t * 8);
            acc[ct] = __builtin_amdgcn_mfma_f32_16x16x32_f16(ahv, bh, acc[ct], 0, 0, 0);
            acc[ct] = __builtin_amdgcn_mfma_f32_16x16x32_f16(ahv, bl, acc[ct], 0, 0, 0);
        }
    }

    float asv[4], adv[4];
    #pragma unroll
    for (int ct = 0; ct < 4; ++ct) {
        asv[ct] = as2[ct * 16 + (t & 15)];
        adv[ct] = ad2[ct * 16 + (t & 15)];
    }
    int rbase = n0 + (t >> 4) * 4;
    #pragma unroll
    for (int r = 0; r < 4; ++r) {
        int n = rbase + r;
        float ps = 0.f, pd = 0.f;
        #pragma unroll
        for (int ct = 0; ct < 4; ++ct) {
            float v = acc[ct][r];
            h2[(size_t)n * 64 + ct * 16 + (t & 15)] = __float2half(v);
            ps += v * asv[ct];
            pd += v * adv[ct];
        }
        ps += __shfl_xor(ps, 1); ps += __shfl_xor(ps, 2);
        ps += __shfl_xor(ps, 4); ps += __shfl_xor(ps, 8);
        pd += __shfl_xor(pd, 1); pd += __shfl_xor(pd, 2);
        pd += __shfl_xor(pd, 4); pd += __shfl_xor(pd, 8);
        if ((t & 15) == 0) { s2[n] = ps; t2[n] = pd; }
    }
}

// ---------------- layer-2 node kernel: 1 node per wave ----------------

__global__ __launch_bounds__(256) void l2_kernel(
    const int* __restrict__ row, const int* __restrict__ adj,
    const __half* __restrict__ h2, const float* __restrict__ s2, const float* __restrict__ t2,
    const float* __restrict__ b2, float* __restrict__ out)
{
    int wid = threadIdx.x >> 6, t = threadIdx.x & 63;
    int n = blockIdx.x * 4 + wid;
    int beg = row[n], end = row[n + 1];
    int slot = t >> 3, g = t & 7;
    float sd = t2[n];
    const int e0 = beg + slot;

    float p[RC2];
    uint4 raw[RC2];
    float m = -3e38f;
    #pragma unroll
    for (int it = 0; it < RC2; ++it) {
        int e = e0 + it * 8;
        bool ok = e < end;
        int s = ok ? adj[e] : n;
        float v = ok ? lrelu(s2[s] + sd) : -3e38f;
        p[it] = v;
        m = fmaxf(m, v);
        raw[it] = *reinterpret_cast<const uint4*>(h2 + (size_t)s * 64 + g * 8);
    }
    for (int e = e0 + RC2 * 8; e < end; e += 8)
        m = fmaxf(m, lrelu(s2[adj[e]] + sd));
    m = fmaxf(m, __shfl_xor(m, 8));
    m = fmaxf(m, __shfl_xor(m, 16));
    m = fmaxf(m, __shfl_xor(m, 32));

    float den = 0.f;
    #pragma unroll
    for (int it = 0; it < RC2; ++it) {
        float pe = __expf(p[it] - m);
        p[it] = pe;
        den += pe;
    }
    for (int e = e0 + RC2 * 8; e < end; e += 8)
        den += __expf(lrelu(s2[adj[e]] + sd) - m);
    den += __shfl_xor(den, 8);
    den += __shfl_xor(den, 16);
    den += __shfl_xor(den, 32);
    float inv = 1.f / (den + 1e-16f);

    float a[8] = {0,0,0,0,0,0,0,0};
    #pragma unroll
    for (int it = 0; it < RC2; ++it) fma8raw(raw[it], p[it] * inv, a);
    for (int e = e0 + RC2 * 8; e < end; e += 8) {
        int s = adj[e];
        float alpha = __expf(lrelu(s2[s] + sd) - m) * inv;
        fma8h(h2 + (size_t)s * 64 + g * 8, alpha, a);
    }
    #pragma unroll
    for (int j = 0; j < 8; ++j) {
        a[j] += __shfl_xor(a[j], 8);
        a[j] += __shfl_xor(a[j], 16);
        a[j] += __shfl_xor(a[j], 32);
    }
    if (slot == 0) {
        float4 o0 = make_float4(a[0] + b2[g * 8 + 0], a[1] + b2[g * 8 + 1],
                                a[2] + b2[g * 8 + 2], a[3] + b2[g * 8 + 3]);
        float4 o1 = make_float4(a[4] + b2[g * 8 + 4], a[5] + b2[g * 8 + 5],
                                a[6] + b2[g * 8 + 6], a[7] + b2[g * 8 + 7]);
        float4* op = (float4*)(out + (size_t)n * 64 + g * 8);
        op[0] = o0; op[1] = o1;
    }
}

extern "C" void kernel_launch(void* const* d_in, const int* in_sizes, int n_in,
                              void* d_out, int out_size, void* d_ws, size_t ws_size,
                              hipStream_t stream)
{
    const float* x   = (const float*)d_in[0];
    const int* ei    = (const int*)d_in[1];
    const float* W1  = (const float*)d_in[2];
    const float* as1 = (const float*)d_in[3];
    const float* ad1 = (const float*)d_in[4];
    const float* b1  = (const float*)d_in[5];
    const float* W2  = (const float*)d_in[6];
    const float* as2 = (const float*)d_in[7];
    const float* ad2 = (const float*)d_in[8];
    const float* b2  = (const float*)d_in[9];
    float* out = (float*)d_out;

    char* wsb = (char*)d_ws;
    __half* h1   = (__half*)wsb;                      // N*64 fp16
    __half* h2   = h1 + (size_t)N_NODES * 64;         // N*64 fp16
    __half* ha   = h2 + (size_t)N_NODES * 64;         // N*64 fp16
    __half* w1fH = ha + (size_t)N_NODES * 64;         // 8192
    __half* w1fL = w1fH + 8192;                       // 8192
    __half* w2fH = w1fL + 8192;                       // 4096
    __half* w2fL = w2fH + 4096;                       // 4096
    float*  s1   = (float*)(w2fL + 4096);             // N*8
    float*  t1   = s1 + N_NODES * 8;                  // N*8
    float*  s2   = t1 + N_NODES * 8;                  // N
    float*  t2   = s2 + N_NODES;                      // N
    int*    cursor = (int*)(t2 + N_NODES);            // 16*NB (line-padded)
    int*    rowp   = cursor + 16 * NB;                // N+1
    int*    adj    = rowp + N_NODES + 1;              // ET
    int*    ebuf   = adj + ET;                        // NB*CAP

    prep_kernel<<<49, 256, 0, stream>>>(W1, W2, w1fH, w1fL, w2fH, w2fL, cursor);

    cl1_kernel<<<HB + LIN1_BLOCKS, 256, 0, stream>>>(ei, cursor, ebuf, x, w1fH, w1fL,
                                                     as1, ad1, h1, s1, t1);

    p2_kernel<<<NB, 512, 0, stream>>>(cursor, ebuf, rowp, adj);

    l1_kernel<<<N_NODES / 4, 256, 0, stream>>>(rowp, adj, h1, s1, t1, b1, ha);

    lin2_kernel<<<LIN1_BLOCKS, 256, 0, stream>>>(ha, w2fH, w2fL, as2, ad2, h2, s2, t2);

    l2_kernel<<<N_NODES / 4, 256, 0, stream>>>(rowp, adj, h2, s2, t2, b2, out);
}